// Round 4
// baseline (320.179 us; speedup 1.0000x reference)
//
#include <hip/hip_runtime.h>

// Problem constants (match reference)
#define BATCH    64
#define HEIGHT   512
#define WIDTH    512
#define CHAN     3
#define PATCH    8
#define NPH      64
#define NPW      64
#define NP_TOT   4096          // NPH*NPW
#define NUM_MASK 3072          // 0.75 * NP_TOT

#define PER_IMG4 (HEIGHT * WIDTH * CHAN / 4)   // 196608 float4 per image
#define PER_ROW4 (WIDTH * CHAN / 4)            // 384 float4 per row

#define BLOCKS_PER_IMG 48
#define CHUNK4 (PER_IMG4 / BLOCKS_PER_IMG)     // 4096 float4 per block
#define ITERS  (CHUNK4 / 256)                  // 16

// Native vector type so __builtin_nontemporal_store emits global_store_dwordx4 nt
typedef float f4 __attribute__((ext_vector_type(4)));

// Single fused kernel: per-workgroup LDS patch-mask rebuild + masked copy.
// Output stores are NON-TEMPORAL: 192 MiB of streaming writes would otherwise
// write-allocate in L2/L3 and evict the input the harness just restored into
// cache; nt keeps the input L3-resident for the 25% of lanes that load it.
__global__ __launch_bounds__(256)
void rm_fused(const f4* __restrict__ in,
              f4* __restrict__ out,
              const int* __restrict__ mask_indices) {
    __shared__ unsigned char smask[NP_TOT];    // 4 KB

    const int b   = blockIdx.x / BLOCKS_PER_IMG;
    const int blk = blockIdx.x - b * BLOCKS_PER_IMG;
    const int t   = threadIdx.x;

    // 1) LDS mask := 1 (1024 dwords, 4 per thread)
    unsigned int* sm32 = (unsigned int*)smask;
#pragma unroll
    for (int i = 0; i < 4; ++i) sm32[i * 256 + t] = 0x01010101u;
    __syncthreads();

    // 2) scatter zeros (12 coalesced index loads per thread; permutation
    //    prefix => distinct indices => byte stores race-free, no atomics)
    const int* idx = mask_indices + b * NUM_MASK;
#pragma unroll
    for (int i = 0; i < 12; ++i) smask[idx[i * 256 + t]] = (unsigned char)0;
    __syncthreads();

    // 3) masked copy of this block's 4096 float4.
    //    Maintain (y, x4) incrementally: l += 256 each iter, and since
    //    PER_ROW4 = 384, x4 either +256 (same row) or -128 (next row).
    const int img_base = b * PER_IMG4;
    int l  = blk * CHUNK4 + t;                 // image-local float4 index
    int y  = l / PER_ROW4;
    int x4 = l - y * PER_ROW4;
#pragma unroll 4
    for (int i = 0; i < ITERS; ++i) {
        int px = x4 / 6;                       // 6 float4 per patch along x
        int py = y >> 3;                       // 8 rows per patch
        unsigned char m = smask[(py << 6) + px];
        f4 v = (f4)(0.f);
        if (m) v = in[img_base + l];           // exec-masked load (L3-hit)
        __builtin_nontemporal_store(v, &out[img_base + l]);
        // advance by 256 float4
        l += 256;
        if (x4 < 128) { x4 += 256; }
        else          { x4 -= 128; y += 1; }
    }
}

extern "C" void kernel_launch(void* const* d_in, const int* in_sizes, int n_in,
                              void* d_out, int out_size, void* d_ws, size_t ws_size,
                              hipStream_t stream) {
    const float* images       = (const float*)d_in[0];
    const int*   mask_indices = (const int*)d_in[1];
    float*       out          = (float*)d_out;

    rm_fused<<<BATCH * BLOCKS_PER_IMG, 256, 0, stream>>>(
        (const f4*)images, (f4*)out, mask_indices);
}